// Round 23
// baseline (364.216 us; speedup 1.0000x reference)
//
#include <hip/hip_runtime.h>
#include <hip/hip_bf16.h>

// GraphMatchingLayer, round 23: r22 verbatim (290us best) with ONE change:
// edge kernel __launch_bounds__(256, 8) (was 4). r22 counters: edge occupancy
// 46%, VGPR 40, LDS 0, nothing saturated -> latency-bound on single-touch
// random ea reads; only my own min-waves hint capped residency. Doubling
// resident waves doubles in-flight random loads -> push toward the ~100us
// random-BW floor. If null: scheduler-capped -> design is at its structural
// floor (scatter transaction wall 130 + ea random-read floor ~100 + node 25).

#define TPB 256
#define MAXD 64
#define EDGE_BLOCKS 2048
#define SCAT_BLOCKS 2048
#define PREP_BLOCKS 1024
#define NODE_BLOCKS 1024

typedef float v2f __attribute__((ext_vector_type(2)));
typedef float v4f __attribute__((ext_vector_type(4)));
typedef __attribute__((ext_vector_type(8))) short s8v;   // 8 bf16 (4 VGPRs)
typedef __attribute__((ext_vector_type(4))) float f4v;   // MFMA C/D
typedef __attribute__((ext_vector_type(4))) unsigned int u4v;
typedef unsigned int uint32;
typedef unsigned short ushort16;

// 32-wide dense segment (weights via wave-uniform address -> scalar loads)
#define SEG32(SRC, NCH, KB, W, COL, ACC)                                \
  for (int kc_ = 0; kc_ < (NCH); ++kc_) {                               \
    const float4 a_ = ((const float4*)(SRC))[kc_];                      \
    const float av_[4] = {a_.x, a_.y, a_.z, a_.w};                      \
    _Pragma("unroll")                                                   \
    for (int j_ = 0; j_ < 4; ++j_) {                                    \
      const float ak_ = av_[j_];                                        \
      const float* wr_ = (W) + ((KB) + kc_ * 4 + j_) * 64 + (COL);      \
      _Pragma("unroll")                                                 \
      for (int cc_ = 0; cc_ < 32; ++cc_)                                \
        ACC[cc_] = fmaf(ak_, wr_[cc_], ACC[cc_]);                       \
    }                                                                   \
  }

__device__ __forceinline__ uint32 pk_bf16(float a, float b) {
  uint32 ua = __float_as_uint(a);
  uint32 ub = __float_as_uint(b);
  ua = ua + 0x7FFFu + ((ua >> 16) & 1u);      // RNE to bf16
  ub = ub + 0x7FFFu + ((ub >> 16) & 1u);
  return (ub & 0xFFFF0000u) | (ua >> 16);     // low=a, high=b
}

__device__ __forceinline__ short f2bf(float f) {
  uint32 u = __float_as_uint(f);
  u = u + 0x7FFFu + ((u >> 16) & 1u);
  return (short)(u >> 16);
}

// ---------------- fused scatter (batched) + U/Vb prep ----------------

__global__ __launch_bounds__(TPB)
void k_sp(const int* __restrict__ ei, int* __restrict__ cnt,
          int2* __restrict__ ec,
          const float* __restrict__ x,
          const float* __restrict__ ew1, const float* __restrict__ eb1,
          float* __restrict__ U, uint32* __restrict__ Vb,
          int E, int N)
{
  const int bid = blockIdx.x;
  const int role = bid % 3;                 // 0,1 -> scatter; 2 -> prep
  const int tid = threadIdx.x;

  if (role < 2) {
    const int vid = (bid / 3) * 2 + role;
    const int stride = SCAT_BLOCKS * TPB;
    const int base = vid * TPB + tid;

    for (int e0 = base; e0 < E; e0 += 4 * stride) {
      int ee[4], rr[4], cc2[4], kk[4];
      bool ok[4];
      #pragma unroll
      for (int j = 0; j < 4; ++j) {
        ee[j] = e0 + j * stride;
        ok[j] = ee[j] < E;
      }
      #pragma unroll
      for (int j = 0; j < 4; ++j) {
        rr[j]  = ok[j] ? ei[ee[j]]     : 0;
        cc2[j] = ok[j] ? ei[E + ee[j]] : 0;
      }
      #pragma unroll
      for (int j = 0; j < 4; ++j)
        if (ok[j]) kk[j] = atomicAdd(&cnt[rr[j]], 1);
      #pragma unroll
      for (int j = 0; j < 4; ++j)
        if (ok[j] && kk[j] < MAXD)
          ec[(size_t)rr[j] * MAXD + kk[j]] = make_int2(ee[j], cc2[j]);
    }
  } else {
    const int vid = bid / 3;
    const int lane = tid & 63;
    const int wid  = __builtin_amdgcn_readfirstlane(tid >> 6);
    const int nunits = 4 * ((N + 63) / 64);
    const int wstride = PREP_BLOCKS * 4;

    for (int unit = vid * 4 + wid; unit < nunits; unit += wstride) {
      const int q = unit & 3;
      const int n = (unit >> 2) * 64 + lane;
      if (n >= N) continue;

      const int uv = q >> 1;
      const int h = (q & 1) * 32;
      const float* W = ew1 + uv * 64 * 64;

      float acc[32];
      if (uv) {
        #pragma unroll
        for (int j = 0; j < 32; ++j) acc[j] = 0.f;
      } else {
        #pragma unroll
        for (int j = 0; j < 32; ++j) acc[j] = eb1[h + j];
      }
      SEG32(x + (size_t)n * 64, 16, 0, W, h, acc)

      if (uv) {
        uint32 pk[16];
        #pragma unroll
        for (int j = 0; j < 16; ++j)
          pk[j] = pk_bf16(acc[2 * j], acc[2 * j + 1]);
        u4v* d4 = (u4v*)(Vb + (size_t)n * 32 + (h >> 1));
        #pragma unroll
        for (int c4 = 0; c4 < 4; ++c4) {
          u4v o = {pk[c4*4+0], pk[c4*4+1], pk[c4*4+2], pk[c4*4+3]};
          d4[c4] = o;
        }
      } else {
        float* dst = U + (size_t)n * 64 + h;
        float4* d4 = (float4*)dst;
        #pragma unroll
        for (int c4 = 0; c4 < 8; ++c4)
          d4[c4] = make_float4(acc[c4*4+0], acc[c4*4+1], acc[c4*4+2], acc[c4*4+3]);
      }
    }
  }
}

// ---------------- edge phase: MFMA, bf16 V gather ----------------

__global__ __launch_bounds__(TPB, 8)     // was 4: free the resident-wave cap
void k_edge_mfma4(const float* __restrict__ U, const uint32* __restrict__ Vb,
                  const float* __restrict__ ea, const int2* __restrict__ ec,
                  const float* __restrict__ ew1,
                  const int* __restrict__ cnt,
                  float* __restrict__ H, int N)
{
  const int lane = threadIdx.x & 63;
  const int wid  = __builtin_amdgcn_readfirstlane(threadIdx.x >> 6);
  const int m16  = lane & 15;
  const int g4   = lane >> 4;

  // B fragments: W1c (32x64) bf16; lane l, elem j -> B[k=g4*8+j][ch=t*16+m16]
  s8v bfrag[4];
  #pragma unroll
  for (int t = 0; t < 4; ++t) {
    #pragma unroll
    for (int j = 0; j < 8; ++j)
      bfrag[t][j] = f2bf(ew1[(128 + g4 * 8 + j) * 64 + t * 16 + m16]);
  }
  asm volatile("" : "+v"(bfrag[0]), "+v"(bfrag[1]),
                    "+v"(bfrag[2]), "+v"(bfrag[3]));

  const ushort16* vbp = (const ushort16*)Vb;
  const int wstride = gridDim.x * 4;

  for (int n = blockIdx.x * 4 + wid; n < N; n += wstride) {
    int d = __builtin_amdgcn_readfirstlane(cnt[n]);
    d = (d < MAXD) ? d : MAXD;

    float uvv[4];
    #pragma unroll
    for (int t = 0; t < 4; ++t) uvv[t] = U[(size_t)n * 64 + t * 16 + m16];

    const int2* ecp = ec + (size_t)n * MAXD;
    float hs[4] = {0.f, 0.f, 0.f, 0.f};
    const int ntile = (d + 15) >> 4;

    for (int tile = 0; tile < ntile; ++tile) {
      const int sbase = tile * 16;

      const bool rowok = (sbase + m16) < d;
      const int eidr = rowok ? ecp[sbase + m16].x : 0;

      // A fragment: 32B of ea row eidr at k-offset g4*8, converted to bf16
      const float4* ear = (const float4*)(ea + (size_t)eidr * 32 + g4 * 8);
      const float4 fa = ear[0];
      const float4 fb = ear[1];
      u4v ua;
      ua.x = pk_bf16(fa.x, fa.y);
      ua.y = pk_bf16(fa.z, fa.w);
      ua.z = pk_bf16(fb.x, fb.y);
      ua.w = pk_bf16(fb.z, fb.w);
      const s8v afrag = __builtin_bit_cast(s8v, ua);

      const int4 c01 = *(const int4*)(ecp + sbase + g4 * 4);
      const int4 c23 = *(const int4*)(ecp + sbase + g4 * 4 + 2);
      const int ca[4] = {c01.y, c01.w, c23.y, c23.w};
      const int rg0 = sbase + g4 * 4;

      #pragma unroll
      for (int t = 0; t < 4; ++t) {
        f4v dd = __builtin_amdgcn_mfma_f32_16x16x32_bf16(
            afrag, bfrag[t], (f4v){0.f, 0.f, 0.f, 0.f}, 0, 0, 0);
        const int ch = t * 16 + m16;
        #pragma unroll
        for (int j = 0; j < 4; ++j) {
          const int rg = rg0 + j;
          const int cs = (rg < d) ? ca[j] : 0;
          const uint32 vu = vbp[(size_t)cs * 64 + ch];      // bf16 gather
          const float vvv = __uint_as_float(vu << 16);
          const float h = fmaxf(dd[j] + uvv[t] + vvv, 0.f);
          hs[t] += (rg < d) ? h : 0.f;
        }
      }
    }

    #pragma unroll
    for (int t = 0; t < 4; ++t) {
      hs[t] += __shfl_xor(hs[t], 16);
      hs[t] += __shfl_xor(hs[t], 32);
    }

    float hv = hs[0];
    hv = (g4 == 1) ? hs[1] : hv;
    hv = (g4 == 2) ? hs[2] : hv;
    hv = (g4 == 3) ? hs[3] : hv;
    H[(size_t)n * 64 + g4 * 16 + m16] = hv;
  }
}

// ---------------- node MLP (frozen) ----------------

__global__ __launch_bounds__(TPB)
void k_node4(const float* __restrict__ x, const float* __restrict__ Hin,
             const int* __restrict__ deg,
             const float* __restrict__ ew2, const float* __restrict__ eb2,
             const float* __restrict__ nw1, const float* __restrict__ nb1,
             const float* __restrict__ nw2, const float* __restrict__ nb2,
             float* __restrict__ out, int N)
{
  __shared__ float sb[2][64 * 65];

  const int tid  = threadIdx.x;
  const int wv   = __builtin_amdgcn_readfirstlane(tid >> 6);
  const int lane = tid & 63;
  const int grp  = wv >> 1;
  const int h    = (wv & 1) * 32;

  for (int base = blockIdx.x * 128; base < N; base += gridDim.x * 128) {
    const int n  = base + grp * 64 + lane;
    const bool valid = (n < N);
    const int nn = valid ? n : (N - 1);

    float* srow = &sb[grp][lane * 65];

    float acc[32];
    const float dg = (float)min(deg[nn], MAXD);
    #pragma unroll
    for (int j = 0; j < 32; ++j) acc[j] = dg * eb2[h + j];
    SEG32(Hin + (size_t)nn * 64, 16, 0, ew2, h, acc)

    #pragma unroll
    for (int j = 0; j < 32; ++j) srow[h + j] = acc[j];
    __syncthreads();

    float bcc[32];
    #pragma unroll
    for (int j = 0; j < 32; ++j) bcc[j] = nb1[h + j];
    SEG32(x + (size_t)nn * 64, 16, 0, nw1, h, bcc)
    for (int k = 0; k < 64; ++k) {
      const float ak = srow[k];
      const float* wr = nw1 + (64 + k) * 64 + h;
      #pragma unroll
      for (int cc = 0; cc < 32; ++cc) bcc[cc] = fmaf(ak, wr[cc], bcc[cc]);
    }
    __syncthreads();

    #pragma unroll
    for (int j = 0; j < 32; ++j) srow[h + j] = fmaxf(bcc[j], 0.f);
    __syncthreads();

    float occ[32];
    #pragma unroll
    for (int j = 0; j < 32; ++j) occ[j] = nb2[h + j];
    for (int k = 0; k < 64; ++k) {
      const float ak = srow[k];
      const float* wr = nw2 + k * 64 + h;
      #pragma unroll
      for (int cc = 0; cc < 32; ++cc) occ[cc] = fmaf(ak, wr[cc], occ[cc]);
    }

    if (valid) {
      float4* ov = (float4*)(out + (size_t)n * 64 + h);
      #pragma unroll
      for (int c4 = 0; c4 < 8; ++c4)
        ov[c4] = make_float4(occ[c4*4+0], occ[c4*4+1], occ[c4*4+2], occ[c4*4+3]);
    }
    __syncthreads();
  }
}

// ---------------- launch ----------------

extern "C" void kernel_launch(void* const* d_in, const int* in_sizes, int n_in,
                              void* d_out, int out_size, void* d_ws, size_t ws_size,
                              hipStream_t stream) {
  const float* x   = (const float*)d_in[0];
  const int*   ei  = (const int*)d_in[1];
  const float* ea  = (const float*)d_in[2];
  const float* ew1 = (const float*)d_in[3];
  const float* eb1 = (const float*)d_in[4];
  const float* ew2 = (const float*)d_in[5];
  const float* eb2 = (const float*)d_in[6];
  const float* nw1 = (const float*)d_in[7];
  const float* nb1 = (const float*)d_in[8];
  const float* nw2 = (const float*)d_in[9];
  const float* nb2 = (const float*)d_in[10];
  float* out = (float*)d_out;

  const int N = in_sizes[0] / 64;   // 100000
  const int E = in_sizes[1] / 2;    // 1600000

  // workspace layout: U | Vb | cnt | ec  (~90 MB)
  float* U    = (float*)d_ws;                      // N*64 f32
  uint32* Vb  = (uint32*)(U + (size_t)N * 64);     // N*32 uints (bf16 pairs)
  int* cnt    = (int*)(Vb + (size_t)N * 32);       // N
  int2* ec    = (int2*)(cnt + N);                  // N*MAXD int2
  float* H    = out;

  hipMemsetAsync(cnt, 0, (size_t)N * sizeof(int), stream);

  k_sp<<<3 * PREP_BLOCKS, TPB, 0, stream>>>(
      ei, cnt, ec, x, ew1, eb1, U, Vb, E, N);

  k_edge_mfma4<<<EDGE_BLOCKS, TPB, 0, stream>>>(
      U, Vb, ea, ec, ew1, cnt, H, N);

  k_node4<<<NODE_BLOCKS, TPB, 0, stream>>>(
      x, H, cnt, ew2, eb2, nw1, nb1, nw2, nb2, out, N);
}

// Round 24
// 286.478 us; speedup vs baseline: 1.2714x; 1.2714x over previous
//
#include <hip/hip_runtime.h>
#include <hip/hip_bf16.h>

// GraphMatchingLayer, round 24: REVERT to round-22 exactly (best: 290us).
// r23 post-mortem: forcing 8 waves/EU squeezed VGPR 40->32, serializing
// per-wave in-flight loads -> edge 132->207us despite 80% occupancy.
// Lesson: per-wave ILP (register-held outstanding loads) beats resident-wave
// count for this random-read kernel; (TPB,4) was the sweet spot.
// Final structure:
//   k_sp:        fused batched slot-scatter (transaction wall ~130us,
//                probed 4 ways) + U/Vb prep (V packed bf16)
//   k_edge_mfma4: 16-edge-tile MFMA edge MLP, direct random ea reads with
//                in-register bf16 conversion, bf16 V gather (~132us,
//                latency-bound, nothing saturated)
//   k_node4:     two-half-wave node MLP (~25us)

#define TPB 256
#define MAXD 64
#define EDGE_BLOCKS 2048
#define SCAT_BLOCKS 2048
#define PREP_BLOCKS 1024
#define NODE_BLOCKS 1024

typedef float v2f __attribute__((ext_vector_type(2)));
typedef float v4f __attribute__((ext_vector_type(4)));
typedef __attribute__((ext_vector_type(8))) short s8v;   // 8 bf16 (4 VGPRs)
typedef __attribute__((ext_vector_type(4))) float f4v;   // MFMA C/D
typedef __attribute__((ext_vector_type(4))) unsigned int u4v;
typedef unsigned int uint32;
typedef unsigned short ushort16;

// 32-wide dense segment (weights via wave-uniform address -> scalar loads)
#define SEG32(SRC, NCH, KB, W, COL, ACC)                                \
  for (int kc_ = 0; kc_ < (NCH); ++kc_) {                               \
    const float4 a_ = ((const float4*)(SRC))[kc_];                      \
    const float av_[4] = {a_.x, a_.y, a_.z, a_.w};                      \
    _Pragma("unroll")                                                   \
    for (int j_ = 0; j_ < 4; ++j_) {                                    \
      const float ak_ = av_[j_];                                        \
      const float* wr_ = (W) + ((KB) + kc_ * 4 + j_) * 64 + (COL);      \
      _Pragma("unroll")                                                 \
      for (int cc_ = 0; cc_ < 32; ++cc_)                                \
        ACC[cc_] = fmaf(ak_, wr_[cc_], ACC[cc_]);                       \
    }                                                                   \
  }

__device__ __forceinline__ uint32 pk_bf16(float a, float b) {
  uint32 ua = __float_as_uint(a);
  uint32 ub = __float_as_uint(b);
  ua = ua + 0x7FFFu + ((ua >> 16) & 1u);      // RNE to bf16
  ub = ub + 0x7FFFu + ((ub >> 16) & 1u);
  return (ub & 0xFFFF0000u) | (ua >> 16);     // low=a, high=b
}

__device__ __forceinline__ short f2bf(float f) {
  uint32 u = __float_as_uint(f);
  u = u + 0x7FFFu + ((u >> 16) & 1u);
  return (short)(u >> 16);
}

// ---------------- fused scatter (batched) + U/Vb prep ----------------

__global__ __launch_bounds__(TPB)
void k_sp(const int* __restrict__ ei, int* __restrict__ cnt,
          int2* __restrict__ ec,
          const float* __restrict__ x,
          const float* __restrict__ ew1, const float* __restrict__ eb1,
          float* __restrict__ U, uint32* __restrict__ Vb,
          int E, int N)
{
  const int bid = blockIdx.x;
  const int role = bid % 3;                 // 0,1 -> scatter; 2 -> prep
  const int tid = threadIdx.x;

  if (role < 2) {
    const int vid = (bid / 3) * 2 + role;
    const int stride = SCAT_BLOCKS * TPB;
    const int base = vid * TPB + tid;

    for (int e0 = base; e0 < E; e0 += 4 * stride) {
      int ee[4], rr[4], cc2[4], kk[4];
      bool ok[4];
      #pragma unroll
      for (int j = 0; j < 4; ++j) {
        ee[j] = e0 + j * stride;
        ok[j] = ee[j] < E;
      }
      #pragma unroll
      for (int j = 0; j < 4; ++j) {
        rr[j]  = ok[j] ? ei[ee[j]]     : 0;
        cc2[j] = ok[j] ? ei[E + ee[j]] : 0;
      }
      #pragma unroll
      for (int j = 0; j < 4; ++j)
        if (ok[j]) kk[j] = atomicAdd(&cnt[rr[j]], 1);
      #pragma unroll
      for (int j = 0; j < 4; ++j)
        if (ok[j] && kk[j] < MAXD)
          ec[(size_t)rr[j] * MAXD + kk[j]] = make_int2(ee[j], cc2[j]);
    }
  } else {
    const int vid = bid / 3;
    const int lane = tid & 63;
    const int wid  = __builtin_amdgcn_readfirstlane(tid >> 6);
    const int nunits = 4 * ((N + 63) / 64);
    const int wstride = PREP_BLOCKS * 4;

    for (int unit = vid * 4 + wid; unit < nunits; unit += wstride) {
      const int q = unit & 3;
      const int n = (unit >> 2) * 64 + lane;
      if (n >= N) continue;

      const int uv = q >> 1;
      const int h = (q & 1) * 32;
      const float* W = ew1 + uv * 64 * 64;

      float acc[32];
      if (uv) {
        #pragma unroll
        for (int j = 0; j < 32; ++j) acc[j] = 0.f;
      } else {
        #pragma unroll
        for (int j = 0; j < 32; ++j) acc[j] = eb1[h + j];
      }
      SEG32(x + (size_t)n * 64, 16, 0, W, h, acc)

      if (uv) {
        // V half -> bf16 packed: 16 uints
        uint32 pk[16];
        #pragma unroll
        for (int j = 0; j < 16; ++j)
          pk[j] = pk_bf16(acc[2 * j], acc[2 * j + 1]);
        u4v* d4 = (u4v*)(Vb + (size_t)n * 32 + (h >> 1));
        #pragma unroll
        for (int c4 = 0; c4 < 4; ++c4) {
          u4v o = {pk[c4*4+0], pk[c4*4+1], pk[c4*4+2], pk[c4*4+3]};
          d4[c4] = o;
        }
      } else {
        float* dst = U + (size_t)n * 64 + h;
        float4* d4 = (float4*)dst;
        #pragma unroll
        for (int c4 = 0; c4 < 8; ++c4)
          d4[c4] = make_float4(acc[c4*4+0], acc[c4*4+1], acc[c4*4+2], acc[c4*4+3]);
      }
    }
  }
}

// ---------------- edge phase: MFMA, bf16 V gather ----------------

__global__ __launch_bounds__(TPB, 4)     // (TPB,4): the measured ILP sweet spot
void k_edge_mfma4(const float* __restrict__ U, const uint32* __restrict__ Vb,
                  const float* __restrict__ ea, const int2* __restrict__ ec,
                  const float* __restrict__ ew1,
                  const int* __restrict__ cnt,
                  float* __restrict__ H, int N)
{
  const int lane = threadIdx.x & 63;
  const int wid  = __builtin_amdgcn_readfirstlane(threadIdx.x >> 6);
  const int m16  = lane & 15;
  const int g4   = lane >> 4;

  // B fragments: W1c (32x64) bf16; lane l, elem j -> B[k=g4*8+j][ch=t*16+m16]
  s8v bfrag[4];
  #pragma unroll
  for (int t = 0; t < 4; ++t) {
    #pragma unroll
    for (int j = 0; j < 8; ++j)
      bfrag[t][j] = f2bf(ew1[(128 + g4 * 8 + j) * 64 + t * 16 + m16]);
  }
  asm volatile("" : "+v"(bfrag[0]), "+v"(bfrag[1]),
                    "+v"(bfrag[2]), "+v"(bfrag[3]));

  const ushort16* vbp = (const ushort16*)Vb;
  const int wstride = gridDim.x * 4;

  for (int n = blockIdx.x * 4 + wid; n < N; n += wstride) {
    int d = __builtin_amdgcn_readfirstlane(cnt[n]);
    d = (d < MAXD) ? d : MAXD;

    float uvv[4];
    #pragma unroll
    for (int t = 0; t < 4; ++t) uvv[t] = U[(size_t)n * 64 + t * 16 + m16];

    const int2* ecp = ec + (size_t)n * MAXD;
    float hs[4] = {0.f, 0.f, 0.f, 0.f};
    const int ntile = (d + 15) >> 4;

    for (int tile = 0; tile < ntile; ++tile) {
      const int sbase = tile * 16;

      const bool rowok = (sbase + m16) < d;
      const int eidr = rowok ? ecp[sbase + m16].x : 0;

      // A fragment: 32B of ea row eidr at k-offset g4*8, converted to bf16
      const float4* ear = (const float4*)(ea + (size_t)eidr * 32 + g4 * 8);
      const float4 fa = ear[0];
      const float4 fb = ear[1];
      u4v ua;
      ua.x = pk_bf16(fa.x, fa.y);
      ua.y = pk_bf16(fa.z, fa.w);
      ua.z = pk_bf16(fb.x, fb.y);
      ua.w = pk_bf16(fb.z, fb.w);
      const s8v afrag = __builtin_bit_cast(s8v, ua);

      const int4 c01 = *(const int4*)(ecp + sbase + g4 * 4);
      const int4 c23 = *(const int4*)(ecp + sbase + g4 * 4 + 2);
      const int ca[4] = {c01.y, c01.w, c23.y, c23.w};
      const int rg0 = sbase + g4 * 4;

      #pragma unroll
      for (int t = 0; t < 4; ++t) {
        f4v dd = __builtin_amdgcn_mfma_f32_16x16x32_bf16(
            afrag, bfrag[t], (f4v){0.f, 0.f, 0.f, 0.f}, 0, 0, 0);
        const int ch = t * 16 + m16;
        #pragma unroll
        for (int j = 0; j < 4; ++j) {
          const int rg = rg0 + j;
          const int cs = (rg < d) ? ca[j] : 0;
          const uint32 vu = vbp[(size_t)cs * 64 + ch];      // bf16 gather
          const float vvv = __uint_as_float(vu << 16);
          const float h = fmaxf(dd[j] + uvv[t] + vvv, 0.f);
          hs[t] += (rg < d) ? h : 0.f;
        }
      }
    }

    #pragma unroll
    for (int t = 0; t < 4; ++t) {
      hs[t] += __shfl_xor(hs[t], 16);
      hs[t] += __shfl_xor(hs[t], 32);
    }

    float hv = hs[0];
    hv = (g4 == 1) ? hs[1] : hv;
    hv = (g4 == 2) ? hs[2] : hv;
    hv = (g4 == 3) ? hs[3] : hv;
    H[(size_t)n * 64 + g4 * 16 + m16] = hv;
  }
}

// ---------------- node MLP (frozen) ----------------

__global__ __launch_bounds__(TPB)
void k_node4(const float* __restrict__ x, const float* __restrict__ Hin,
             const int* __restrict__ deg,
             const float* __restrict__ ew2, const float* __restrict__ eb2,
             const float* __restrict__ nw1, const float* __restrict__ nb1,
             const float* __restrict__ nw2, const float* __restrict__ nb2,
             float* __restrict__ out, int N)
{
  __shared__ float sb[2][64 * 65];

  const int tid  = threadIdx.x;
  const int wv   = __builtin_amdgcn_readfirstlane(tid >> 6);
  const int lane = tid & 63;
  const int grp  = wv >> 1;
  const int h    = (wv & 1) * 32;

  for (int base = blockIdx.x * 128; base < N; base += gridDim.x * 128) {
    const int n  = base + grp * 64 + lane;
    const bool valid = (n < N);
    const int nn = valid ? n : (N - 1);

    float* srow = &sb[grp][lane * 65];

    float acc[32];
    const float dg = (float)min(deg[nn], MAXD);
    #pragma unroll
    for (int j = 0; j < 32; ++j) acc[j] = dg * eb2[h + j];
    SEG32(Hin + (size_t)nn * 64, 16, 0, ew2, h, acc)

    #pragma unroll
    for (int j = 0; j < 32; ++j) srow[h + j] = acc[j];
    __syncthreads();

    float bcc[32];
    #pragma unroll
    for (int j = 0; j < 32; ++j) bcc[j] = nb1[h + j];
    SEG32(x + (size_t)nn * 64, 16, 0, nw1, h, bcc)
    for (int k = 0; k < 64; ++k) {
      const float ak = srow[k];
      const float* wr = nw1 + (64 + k) * 64 + h;
      #pragma unroll
      for (int cc = 0; cc < 32; ++cc) bcc[cc] = fmaf(ak, wr[cc], bcc[cc]);
    }
    __syncthreads();

    #pragma unroll
    for (int j = 0; j < 32; ++j) srow[h + j] = fmaxf(bcc[j], 0.f);
    __syncthreads();

    float occ[32];
    #pragma unroll
    for (int j = 0; j < 32; ++j) occ[j] = nb2[h + j];
    for (int k = 0; k < 64; ++k) {
      const float ak = srow[k];
      const float* wr = nw2 + k * 64 + h;
      #pragma unroll
      for (int cc = 0; cc < 32; ++cc) occ[cc] = fmaf(ak, wr[cc], occ[cc]);
    }

    if (valid) {
      float4* ov = (float4*)(out + (size_t)n * 64 + h);
      #pragma unroll
      for (int c4 = 0; c4 < 8; ++c4)
        ov[c4] = make_float4(occ[c4*4+0], occ[c4*4+1], occ[c4*4+2], occ[c4*4+3]);
    }
    __syncthreads();
  }
}

// ---------------- launch ----------------

extern "C" void kernel_launch(void* const* d_in, const int* in_sizes, int n_in,
                              void* d_out, int out_size, void* d_ws, size_t ws_size,
                              hipStream_t stream) {
  const float* x   = (const float*)d_in[0];
  const int*   ei  = (const int*)d_in[1];
  const float* ea  = (const float*)d_in[2];
  const float* ew1 = (const float*)d_in[3];
  const float* eb1 = (const float*)d_in[4];
  const float* ew2 = (const float*)d_in[5];
  const float* eb2 = (const float*)d_in[6];
  const float* nw1 = (const float*)d_in[7];
  const float* nb1 = (const float*)d_in[8];
  const float* nw2 = (const float*)d_in[9];
  const float* nb2 = (const float*)d_in[10];
  float* out = (float*)d_out;

  const int N = in_sizes[0] / 64;   // 100000
  const int E = in_sizes[1] / 2;    // 1600000

  // workspace layout: U | Vb | cnt | ec  (~90 MB)
  float* U    = (float*)d_ws;                      // N*64 f32
  uint32* Vb  = (uint32*)(U + (size_t)N * 64);     // N*32 uints (bf16 pairs)
  int* cnt    = (int*)(Vb + (size_t)N * 32);       // N
  int2* ec    = (int2*)(cnt + N);                  // N*MAXD int2
  float* H    = out;

  hipMemsetAsync(cnt, 0, (size_t)N * sizeof(int), stream);

  k_sp<<<3 * PREP_BLOCKS, TPB, 0, stream>>>(
      ei, cnt, ec, x, ew1, eb1, U, Vb, E, N);

  k_edge_mfma4<<<EDGE_BLOCKS, TPB, 0, stream>>>(
      U, Vb, ea, ec, ew1, cnt, H, N);

  k_node4<<<NODE_BLOCKS, TPB, 0, stream>>>(
      x, H, cnt, ew2, eb2, nw1, nb1, nw2, nb2, out, N);
}